// Round 10
// baseline (231.789 us; speedup 1.0000x reference)
//
#include <hip/hip_runtime.h>
#include <stdint.h>

// Problem dims (fixed by the reference's setup_inputs)
#define B    8
#define C    80
#define M    100
#define NPIX 16384          // 128*128
#define NT   64             // cells per block
#define BT   256            // threads per block (4 waves)
#define NW   4              // waves per block in init kernel

#define ALPHA_F 0.25f
#define EPS_F   1e-8f

// Order-preserving float -> uint32 map (total order; no NaNs expected here).
__device__ __forceinline__ uint32_t fkey(float f) {
    uint32_t u = __float_as_uint(f);
    return (u & 0x80000000u) ? ~u : (u | 0x80000000u);
}

// ---------------------------------------------------------------------------
// init: one wave per (b,m). cid = first argmax of one-hot row; keys = +inf.
// ---------------------------------------------------------------------------
__global__ __launch_bounds__(256) void init_kernel(
    const float* __restrict__ cls_true,   // (B*M, C)
    int* __restrict__ cids,
    unsigned long long* __restrict__ keys)
{
    const int bm   = blockIdx.x * NW + (threadIdx.x >> 6);
    const int lane = threadIdx.x & 63;
    if (bm >= B * M) return;

    const float* ct = cls_true + (size_t)bm * C;
    // key = (fkey(v) << 32) | (C-1-c): max over keys -> max v, tie -> min c
    const float v0 = ct[lane];
    unsigned long long k =
        ((unsigned long long)fkey(v0) << 32) | (unsigned int)(C - 1 - lane);
    if (lane + 64 < C) {
        const float v1 = ct[lane + 64];
        unsigned long long k1 =
            ((unsigned long long)fkey(v1) << 32) | (unsigned int)(C - 1 - (lane + 64));
        if (k1 > k) k = k1;
    }
    #pragma unroll
    for (int off = 32; off > 0; off >>= 1) {
        unsigned long long o = __shfl_xor(k, off, 64);
        if (o > k) k = o;
    }
    if (lane == 0) {
        cids[bm] = C - 1 - (int)(k & 0xFFFFFFFFull);
        keys[bm] = 0xFFFFFFFFFFFFFFFFull;
    }
}

// ---------------------------------------------------------------------------
// fused match: block = (64-cell tile, b), 256 threads (4 waves).
// Wave w: owns m = (w&1)*64+lane, scans cells (w>>1)*32 .. +31.
// D in LDS as [n][c] (20,480 B): per-pair gather = ds_read_b32 from a fixed
// per-lane base (cid*4 + half*320*32) + compile-time offset j*320. Boxes in
// LDS [n][8] (2,048 B): broadcast reads at imm offsets. 22.5 KB -> 7
// blocks/CU = 28 waves/CU. Uniform control flow; one atomicMin per (m,half).
// ---------------------------------------------------------------------------
__global__ __launch_bounds__(BT, 6) void match_kernel(
    const float* __restrict__ cls_pred,   // (B, NPIX, C)
    const float* __restrict__ loc_pred,   // (B, NPIX, 4)
    const float* __restrict__ loc_true,   // (B, M, 4)
    const int*   __restrict__ cids,       // (B*M)
    unsigned long long* __restrict__ keys)// (B*M)
{
#pragma clang fp contract(off)
    __shared__ float D[NT * C];           // [cell][class], word = n*80+c
    __shared__ float BX[NT * 8];          // [cell][{py1,px1,py2,px2,pa,_,_,_}]

    const int b    = blockIdx.y;
    const int n0   = blockIdx.x * NT;
    const int tid  = threadIdx.x;
    const int lane = tid & 63;
    const int w    = tid >> 6;

    // ---- stage focal class-cost tile: float4 loads; word offset = 4*idx4
    //      (n*80 + c0 == 4*idx4), so LDS writes are linear ds_write_b128 ----
    const float4* src4 = (const float4*)(cls_pred + ((size_t)b * NPIX + n0) * C);
    #pragma unroll
    for (int it = 0; it < NT * C / 4 / BT; ++it) {   // 5 iters
        const int idx4 = it * BT + tid;
        const float4 v = src4[idx4];
        const float pv[4] = { v.x, v.y, v.z, v.w };
        float fo[4];
        #pragma unroll
        for (int jj = 0; jj < 4; ++jj) {
            const float p = pv[jj];
            const float q = 1.0f - p;
            const float pos = (ALPHA_F * (q * q)) * (-logf(p + EPS_F));
            const float neg = ((1.0f - ALPHA_F) * (p * p)) * (-logf(q + EPS_F));
            fo[jj] = pos - neg;
        }
        *(float4*)&D[idx4 * 4] = make_float4(fo[0], fo[1], fo[2], fo[3]);
    }

    // ---- stage per-cell scaled boxes ----
    if (tid < NT) {
        const float inv = 1.0f / 128.0f;
        const float4 lp = *(const float4*)(loc_pred + ((size_t)b * NPIX + n0 + tid) * 4);
        const float py1 = lp.x * inv;
        const float px1 = lp.y * inv;
        const float py2 = lp.z * inv;
        const float px2 = lp.w * inv;
        *(float4*)&BX[tid * 8] = make_float4(py1, px1, py2, px2);
        BX[tid * 8 + 4] = fmaxf(py2 - py1, 0.0f) * fmaxf(px2 - px1, 0.0f);
    }

    // ---- per-lane target (m); clamp inactive lanes to m=0 (junk, masked) ----
    const int  mm  = (w & 1) * 64 + lane;
    const int  bm  = b * M + (mm < M ? mm : 0);
    const int  cid = cids[bm];
    const float4 lt = *(const float4*)(loc_true + (size_t)bm * 4);
    const float ty1 = lt.x, tx1 = lt.y, ty2 = lt.z, tx2 = lt.w;
    const float t_area = fmaxf(ty2 - ty1, 0.0f) * fmaxf(tx2 - tx1, 0.0f);

    __syncthreads();

    // ---- scan: 32 cells of this wave's half, fully unrolled, imm offsets ----
    const int jb = (w >> 1) * (NT / 2);              // 0 or 32
    const float* Dp = &D[jb * C + cid];              // per-lane base
    const float* Bp = &BX[jb * 8];                   // wave-uniform base

    float bestv = __builtin_huge_valf();
    int   bestn = 0;

    #pragma unroll
    for (int j = 0; j < NT / 2; ++j) {
        const float  d  = Dp[j * C];                 // ds_read_b32 offset:j*320
        const float4 bx = *(const float4*)&Bp[j * 8];// broadcast b128
        const float  pa = Bp[j * 8 + 4];             // broadcast b32
        const float py1 = bx.x, px1 = bx.y, py2 = bx.z, px2 = bx.w;

        // reg: sum(|loc_true - loc_p|), left-assoc like np
        const float r = ((fabsf(ty1 - py1) + fabsf(tx1 - px1))
                         + fabsf(ty2 - py2)) + fabsf(tx2 - px2);

        // giou
        const float ih = fmaxf(fminf(py2, ty2) - fmaxf(py1, ty1), 0.0f);
        const float iw = fmaxf(fminf(px2, tx2) - fmaxf(px1, tx1), 0.0f);
        const float inter = ih * iw;
        const float uni   = (pa + t_area) - inter;
        const float iou   = (uni > 0.0f) ? (inter / fmaxf(uni, EPS_F)) : 0.0f;
        const float eh = fmaxf(py2, ty2) - fminf(py1, ty1);
        const float ew = fmaxf(px2, tx2) - fminf(px1, tx1);
        const float enc = eh * ew;
        const float pen = (enc > 0.0f) ? ((enc - uni) / fmaxf(enc, EPS_F)) : 0.0f;
        const float gl  = 1.0f - (iou - pen);

        const float total = ((2.0f * d) + (5.0f * r)) + (2.0f * gl);

        if (total < bestv) { bestv = total; bestn = n0 + jb + j; }  // strict < => first index
    }

    if (mm < M) {
        const unsigned long long key =
            ((unsigned long long)fkey(bestv) << 32) | (unsigned int)bestn;
        atomicMin(&keys[bm], key);
    }
}

// ---------------------------------------------------------------------------
// writeout: unpack to (b, argmin, cid) int32
// ---------------------------------------------------------------------------
__global__ void write_out_kernel(const unsigned long long* __restrict__ keys,
                                 const int* __restrict__ cids,
                                 int* __restrict__ out) {
    int i = blockIdx.x * blockDim.x + threadIdx.x;
    if (i >= B * M) return;
    out[i * 3 + 0] = i / M;
    out[i * 3 + 1] = (int)(keys[i] & 0xFFFFFFFFull);
    out[i * 3 + 2] = cids[i];
}

// ===========================================================================
extern "C" void kernel_launch(void* const* d_in, const int* in_sizes, int n_in,
                              void* d_out, int out_size, void* d_ws, size_t ws_size,
                              hipStream_t stream) {
    const float* cls_pred = (const float*)d_in[0];
    const float* loc_pred = (const float*)d_in[1];
    const float* cls_true = (const float*)d_in[2];
    const float* loc_true = (const float*)d_in[3];
    int* out = (int*)d_out;

    unsigned long long* keys = (unsigned long long*)d_ws;
    int* cids = (int*)((char*)d_ws + (size_t)B * M * sizeof(unsigned long long));

    init_kernel<<<(B * M + NW - 1) / NW, 256, 0, stream>>>(cls_true, cids, keys);
    match_kernel<<<dim3(NPIX / NT, B), BT, 0, stream>>>(
        cls_pred, loc_pred, loc_true, cids, keys);
    write_out_kernel<<<(B * M + 255) / 256, 256, 0, stream>>>(keys, cids, out);
}

// Round 11
// 78.582 us; speedup vs baseline: 2.9497x; 2.9497x over previous
//
#include <hip/hip_runtime.h>
#include <stdint.h>

// Problem dims (fixed by the reference's setup_inputs)
#define B    8
#define C    80
#define M    100
#define NPIX 16384          // 128*128
#define NT   32             // cells per LDS tile
#define KT   2              // tiles per block (double-buffered)
#define BT   128            // threads per block (2 waves)
#define NW   4              // waves per block in init kernel

#define ALPHA_F  0.25f
#define EPS_F    1e-8f
// |exact - fast| <= ~4e-6 (native log <=1ulp-of-log2, rcp 1ulp); 25x margin:
#define CERT_GAP 1e-4f

// Bank swizzle for class rows: spreads per-cid gathers across banks
#define SWZ(c) ((((c) & 31)) ^ ((((c) >> 5)) << 3))

// Order-preserving float -> uint32 map (total order; no NaNs expected here).
__device__ __forceinline__ uint32_t fkey(float f) {
    uint32_t u = __float_as_uint(f);
    return (u & 0x80000000u) ? ~u : (u | 0x80000000u);
}
__device__ __forceinline__ float unfkey(uint32_t k) {
    return __uint_as_float((k & 0x80000000u) ? (k & 0x7FFFFFFFu) : ~k);
}

// ---------------------------------------------------------------------------
// init: one wave per (b,m). cid = first argmax of one-hot; keys/keys2 = +inf.
// ---------------------------------------------------------------------------
__global__ __launch_bounds__(256) void init_kernel(
    const float* __restrict__ cls_true,   // (B*M, C)
    int* __restrict__ cids,
    unsigned long long* __restrict__ keys,
    unsigned long long* __restrict__ keys2)
{
    const int bm   = blockIdx.x * NW + (threadIdx.x >> 6);
    const int lane = threadIdx.x & 63;
    if (bm >= B * M) return;

    const float* ct = cls_true + (size_t)bm * C;
    const float v0 = ct[lane];
    unsigned long long k =
        ((unsigned long long)fkey(v0) << 32) | (unsigned int)(C - 1 - lane);
    if (lane + 64 < C) {
        const float v1 = ct[lane + 64];
        unsigned long long k1 =
            ((unsigned long long)fkey(v1) << 32) | (unsigned int)(C - 1 - (lane + 64));
        if (k1 > k) k = k1;
    }
    #pragma unroll
    for (int off = 32; off > 0; off >>= 1) {
        unsigned long long o = __shfl_xor(k, off, 64);
        if (o > k) k = o;
    }
    if (lane == 0) {
        cids[bm]  = C - 1 - (int)(k & 0xFFFFFFFFull);
        keys[bm]  = 0xFFFFFFFFFFFFFFFFull;
        keys2[bm] = 0xFFFFFFFFFFFFFFFFull;
    }
}

// ---------------------------------------------------------------------------
// prep: pbox[b][n][8] = {py1,px1,py2,px2,p_area,0,0,0} (scaled).
// ---------------------------------------------------------------------------
__global__ __launch_bounds__(256) void prep_kernel(
    const float* __restrict__ loc_pred,   // (B, NPIX, 4)
    float* __restrict__ pbox)             // (B*NPIX, 8)
{
#pragma clang fp contract(off)
    const int i = blockIdx.x * 256 + threadIdx.x;
    if (i >= B * NPIX) return;
    const float inv = 1.0f / 128.0f;
    const float4 lp = ((const float4*)loc_pred)[i];
    const float py1 = lp.x * inv;
    const float px1 = lp.y * inv;
    const float py2 = lp.z * inv;
    const float px2 = lp.w * inv;
    const float pa  = fmaxf(py2 - py1, 0.0f) * fmaxf(px2 - px1, 0.0f);
    float4* dst = (float4*)pbox + (size_t)i * 2;
    dst[0] = make_float4(py1, px1, py2, px2);
    dst[1] = make_float4(pa, 0.0f, 0.0f, 0.0f);
}

// ---------------------------------------------------------------------------
// fast match (round-7 structure + fast log/div + top-2 certification):
// block = (2 x 32-cell tiles, b), 128 threads, lane-owns-m. D double-buffered
// in swizzled LDS; boxes via wave-uniform loads from pbox. Per lane: top-2
// (b1v,b1n,b2v) over 64 cells; then predicated atomicMin into keys (global
// best) and keys2 (provable global 2nd via loser-forwarding).
// ---------------------------------------------------------------------------
__global__ __launch_bounds__(BT) void match_kernel(
    const float* __restrict__ cls_pred,   // (B, NPIX, C)
    const float* __restrict__ pbox,       // (B*NPIX, 8)
    const float* __restrict__ loc_true,   // (B, M, 4)
    const int*   __restrict__ cids,       // (B*M)
    unsigned long long* __restrict__ keys,
    unsigned long long* __restrict__ keys2)
{
#pragma clang fp contract(off)
    __shared__ float D[2][C * NT];        // 2 x 10,240 B

    const int b      = blockIdx.y;
    const int base_n = blockIdx.x * (NT * KT);
    const int tid    = threadIdx.x;
    const int lane   = tid & 63;
    const int w      = tid >> 6;

    // ---- per-lane target (m) data ----
    const int  mm  = w * 64 + lane;
    const bool act = (mm < M);
    const int  bm  = b * M + (act ? mm : 0);
    int cid = 0, drow = 0, sw = 0;
    float ty1 = 0.f, tx1 = 0.f, ty2 = 0.f, tx2 = 0.f, t_area = 0.f;
    if (act) {
        cid = cids[bm];
        const float4 lt = *(const float4*)(loc_true + (size_t)bm * 4);
        ty1 = lt.x; tx1 = lt.y; ty2 = lt.z; tx2 = lt.w;
        t_area = fmaxf(ty2 - ty1, 0.0f) * fmaxf(tx2 - tx1, 0.0f);
        drow = cid * NT;
        sw   = SWZ(cid) & (NT - 1);
    }

    // ---- stage tile 0 into D[0] (fast log) ----
    {
        const float4* src4 = (const float4*)(cls_pred + ((size_t)b * NPIX + base_n) * C);
        #pragma unroll
        for (int it = 0; it < NT * C / 4 / BT; ++it) {   // 5 iters
            const int idx4 = it * BT + tid;
            const int n    = idx4 / 20;
            const int c0   = (idx4 - n * 20) * 4;
            const float4 v = src4[idx4];
            const float pv[4] = { v.x, v.y, v.z, v.w };
            #pragma unroll
            for (int jj = 0; jj < 4; ++jj) {
                const int c = c0 + jj;
                const float p = pv[jj];
                const float q = 1.0f - p;
                const float pos = (ALPHA_F * (q * q)) * (-__logf(p + EPS_F));
                const float neg = ((1.0f - ALPHA_F) * (p * p)) * (-__logf(q + EPS_F));
                D[0][c * NT + ((n ^ SWZ(c)) & (NT - 1))] = pos - neg;
            }
        }
    }
    __syncthreads();

    float b1v = __builtin_huge_valf();
    float b2v = __builtin_huge_valf();
    int   b1n = 0;

    #pragma unroll
    for (int t = 0; t < KT; ++t) {
        const int cur = t & 1;
        const int tn0 = base_n + t * NT;

        // ---- issue next tile's global loads ----
        float4 ld[5];
        if (t + 1 < KT) {
            const float4* src4 =
                (const float4*)(cls_pred + ((size_t)b * NPIX + tn0 + NT) * C);
            #pragma unroll
            for (int it = 0; it < 5; ++it) ld[it] = src4[it * BT + tid];
        }

        // ---- scan tile t ----
        if (act) {
            const float* pb = pbox + ((size_t)(b * NPIX) + tn0) * 8;
            #pragma unroll 8
            for (int j = 0; j < NT; ++j) {
                const float d   = D[cur][drow + (j ^ sw)];
                const float py1 = pb[j * 8 + 0];
                const float px1 = pb[j * 8 + 1];
                const float py2 = pb[j * 8 + 2];
                const float px2 = pb[j * 8 + 3];
                const float pa  = pb[j * 8 + 4];

                const float r = ((fabsf(ty1 - py1) + fabsf(tx1 - px1))
                                 + fabsf(ty2 - py2)) + fabsf(tx2 - px2);

                const float ih = fmaxf(fminf(py2, ty2) - fmaxf(py1, ty1), 0.0f);
                const float iw = fmaxf(fminf(px2, tx2) - fmaxf(px1, tx1), 0.0f);
                const float inter = ih * iw;
                const float uni   = (pa + t_area) - inter;
                const float iou   = (uni > 0.0f)
                    ? __fdividef(inter, fmaxf(uni, EPS_F)) : 0.0f;
                const float eh = fmaxf(py2, ty2) - fminf(py1, ty1);
                const float ew = fmaxf(px2, tx2) - fminf(px1, tx1);
                const float enc = eh * ew;
                const float pen = (enc > 0.0f)
                    ? __fdividef(enc - uni, fmaxf(enc, EPS_F)) : 0.0f;
                const float gl  = 1.0f - (iou - pen);

                const float total = ((2.0f * d) + (5.0f * r)) + (2.0f * gl);

                if (total < b1v)      { b2v = b1v; b1v = total; b1n = tn0 + j; }
                else if (total < b2v) { b2v = total; }
            }
        }

        // ---- focal compute for next tile (fast log) ----
        if (t + 1 < KT) {
            #pragma unroll
            for (int it = 0; it < 5; ++it) {
                const int idx4 = it * BT + tid;
                const int n    = idx4 / 20;
                const int c0   = (idx4 - n * 20) * 4;
                const float pv[4] = { ld[it].x, ld[it].y, ld[it].z, ld[it].w };
                #pragma unroll
                for (int jj = 0; jj < 4; ++jj) {
                    const int c = c0 + jj;
                    const float p = pv[jj];
                    const float q = 1.0f - p;
                    const float pos = (ALPHA_F * (q * q)) * (-__logf(p + EPS_F));
                    const float neg = ((1.0f - ALPHA_F) * (p * p)) * (-__logf(q + EPS_F));
                    D[1 - cur][c * NT + ((n ^ SWZ(c)) & (NT - 1))] = pos - neg;
                }
            }
            __syncthreads();
        }
    }

    if (act) {
        const unsigned long long k1 =
            ((unsigned long long)fkey(b1v) << 32) | (unsigned int)b1n;
        const unsigned long long k2 = ((unsigned long long)fkey(b2v) << 32);

        const unsigned long long cur1 = keys[bm];   // stale >= final: safe
        unsigned long long loser = k1;
        if (k1 < cur1) {
            const unsigned long long old = atomicMin(&keys[bm], k1);
            loser = (k1 < old) ? old : k1;          // max(k1, old)
        }
        const unsigned long long cand2 = (loser < k2) ? loser : k2;
        const unsigned long long cur2  = keys2[bm]; // stale >= final: safe
        if (cand2 < cur2) atomicMin(&keys2[bm], cand2);
    }
}

// ---------------------------------------------------------------------------
// writeout + certification flags
// ---------------------------------------------------------------------------
__global__ void write_out_kernel(const unsigned long long* __restrict__ keys,
                                 const unsigned long long* __restrict__ keys2,
                                 const int* __restrict__ cids,
                                 int* __restrict__ out,
                                 int* __restrict__ flags) {
    int i = blockIdx.x * blockDim.x + threadIdx.x;
    if (i >= B * M) return;
    out[i * 3 + 0] = i / M;
    out[i * 3 + 1] = (int)(keys[i] & 0xFFFFFFFFull);
    out[i * 3 + 2] = cids[i];
    const float v1 = unfkey((uint32_t)(keys[i] >> 32));
    const float v2 = unfkey((uint32_t)(keys2[i] >> 32));
    flags[i] = (v2 - v1 <= CERT_GAP) ? 1 : 0;
}

// ---------------------------------------------------------------------------
// exact fix: for flagged (b,m) only, exact full scan (precise log/div, same
// expression tree as the always-passing exact rounds); overwrites out[..][1].
// ---------------------------------------------------------------------------
__global__ __launch_bounds__(1024) void exact_fix_kernel(
    const float* __restrict__ cls_pred,   // (B, NPIX, C)
    const float* __restrict__ loc_pred,   // (B, NPIX, 4)
    const float* __restrict__ loc_true,   // (B, M, 4)
    const int*   __restrict__ cids,       // (B*M)
    const int*   __restrict__ flags,
    int* __restrict__ out)
{
#pragma clang fp contract(off)
    const int bm = blockIdx.x;
    if (!flags[bm]) return;               // block-uniform early exit

    const int b   = bm / M;
    const int tid = threadIdx.x;
    const int cid = cids[bm];

    const float4 lt = *(const float4*)(loc_true + (size_t)bm * 4);
    const float ty1 = lt.x, tx1 = lt.y, ty2 = lt.z, tx2 = lt.w;
    const float t_area = fmaxf(ty2 - ty1, 0.0f) * fmaxf(tx2 - tx1, 0.0f);
    const float inv = 1.0f / 128.0f;

    unsigned long long best = 0xFFFFFFFFFFFFFFFFull;

    for (int n = tid; n < NPIX; n += 1024) {
        const float p = cls_pred[((size_t)b * NPIX + n) * C + cid];
        const float q = 1.0f - p;
        const float pos = (ALPHA_F * (q * q)) * (-logf(p + EPS_F));
        const float neg = ((1.0f - ALPHA_F) * (p * p)) * (-logf(q + EPS_F));
        const float d   = pos - neg;

        const float4 lp = *(const float4*)(loc_pred + ((size_t)b * NPIX + n) * 4);
        const float py1 = lp.x * inv;
        const float px1 = lp.y * inv;
        const float py2 = lp.z * inv;
        const float px2 = lp.w * inv;
        const float pa  = fmaxf(py2 - py1, 0.0f) * fmaxf(px2 - px1, 0.0f);

        const float r = ((fabsf(ty1 - py1) + fabsf(tx1 - px1))
                         + fabsf(ty2 - py2)) + fabsf(tx2 - px2);

        const float ih = fmaxf(fminf(py2, ty2) - fmaxf(py1, ty1), 0.0f);
        const float iw = fmaxf(fminf(px2, tx2) - fmaxf(px1, tx1), 0.0f);
        const float inter = ih * iw;
        const float uni   = (pa + t_area) - inter;
        const float iou   = (uni > 0.0f) ? (inter / fmaxf(uni, EPS_F)) : 0.0f;
        const float eh = fmaxf(py2, ty2) - fminf(py1, ty1);
        const float ew = fmaxf(px2, tx2) - fminf(px1, tx1);
        const float enc = eh * ew;
        const float pen = (enc > 0.0f) ? ((enc - uni) / fmaxf(enc, EPS_F)) : 0.0f;
        const float gl  = 1.0f - (iou - pen);

        const float total = ((2.0f * d) + (5.0f * r)) + (2.0f * gl);

        const unsigned long long key =
            ((unsigned long long)fkey(total) << 32) | (unsigned int)n;
        if (key < best) best = key;
    }

    #pragma unroll
    for (int off = 32; off > 0; off >>= 1) {
        unsigned long long o = __shfl_xor(best, off, 64);
        if (o < best) best = o;
    }
    __shared__ unsigned long long red[16];
    if ((tid & 63) == 0) red[tid >> 6] = best;
    __syncthreads();
    if (tid == 0) {
        unsigned long long r = red[0];
        #pragma unroll
        for (int i = 1; i < 16; ++i) if (red[i] < r) r = red[i];
        out[bm * 3 + 1] = (int)(r & 0xFFFFFFFFull);
    }
}

// ===========================================================================
extern "C" void kernel_launch(void* const* d_in, const int* in_sizes, int n_in,
                              void* d_out, int out_size, void* d_ws, size_t ws_size,
                              hipStream_t stream) {
    const float* cls_pred = (const float*)d_in[0];
    const float* loc_pred = (const float*)d_in[1];
    const float* cls_true = (const float*)d_in[2];
    const float* loc_true = (const float*)d_in[3];
    int* out = (int*)d_out;

    // ws: keys(6400) | keys2(6400) | cids(3200) | flags(3200) | pad | pbox(4.2MB)
    unsigned long long* keys  = (unsigned long long*)d_ws;
    unsigned long long* keys2 = (unsigned long long*)((char*)d_ws + 6400);
    int*   cids  = (int*)((char*)d_ws + 12800);
    int*   flags = (int*)((char*)d_ws + 16000);
    float* pbox  = (float*)((char*)d_ws + 32768);

    init_kernel<<<(B * M + NW - 1) / NW, 256, 0, stream>>>(cls_true, cids, keys, keys2);
    prep_kernel<<<(B * NPIX + 255) / 256, 256, 0, stream>>>(loc_pred, pbox);
    match_kernel<<<dim3(NPIX / (NT * KT), B), BT, 0, stream>>>(
        cls_pred, pbox, loc_true, cids, keys, keys2);
    write_out_kernel<<<(B * M + 255) / 256, 256, 0, stream>>>(keys, keys2, cids, out, flags);
    exact_fix_kernel<<<B * M, 1024, 0, stream>>>(
        cls_pred, loc_pred, loc_true, cids, flags, out);
}